// Round 7
// baseline (232.011 us; speedup 1.0000x reference)
//
#include <hip/hip_runtime.h>

// SimCLR fused pipeline, round 7: canonical LDS-staged structures.
// sim: 4 waves x 32 rows (A=32 VGPR/wave), 512-col slice, B double-buffered
//      in LDS (16 stages x 32 cols, padded stride), 1 barrier/stage.
// gemm2: W2 K-chunks double-buffered in LDS, 8 waves x (16 rows x 16 cols),
//      Y prefetched 1 stage ahead, 8-wave LDS norm combine.
// gemm1: MFMA bf16x2 + fused BN col-sum atomics (unchanged).

#define NB   4096
#define DIN  192
#define DHID 512
#define DOUT 128
#define N2   8192   // 2*NB
#define NSPLIT 16   // sim col-splits; 512 cols per block

typedef short short8 __attribute__((ext_vector_type(8)));   // 8 bf16 (4 VGPRs)
typedef float floatx4 __attribute__((ext_vector_type(4)));  // MFMA C/D frag

__device__ inline float fast_exp2(float x) {
#if __has_builtin(__builtin_amdgcn_exp2f)
    return __builtin_amdgcn_exp2f(x);
#else
    return exp2f(x);
#endif
}

// Truncation-based Dekker split: x ~= hi + lo with |err| < 2^-16 |x|.
__device__ inline void split8(const float* x, short8& hi, short8& lo) {
    #pragma unroll
    for (int j = 0; j < 8; ++j) {
        unsigned int u = __float_as_uint(x[j]);
        float hf = __uint_as_float(u & 0xffff0000u);
        float r = x[j] - hf;                       // exact
        hi[j] = (short)(u >> 16);
        lo[j] = (short)(__float_as_uint(r) >> 16);
    }
}

__device__ inline unsigned short bf16_rne(float x) {
    unsigned int u = __float_as_uint(x);
    return (unsigned short)((u + 0x7fffu + ((u >> 16) & 1u)) >> 16);
}

// ---------------- convert W1, W2 -> hi/lo bf16 ------------------------------
__global__ __launch_bounds__(256) void convert_w(
    const float* __restrict__ W1, const float* __restrict__ W2,
    unsigned short* __restrict__ W1hi, unsigned short* __restrict__ W1lo,
    unsigned short* __restrict__ W2hi, unsigned short* __restrict__ W2lo)
{
    const int NW1 = DHID * DIN / 4;   // 24576 float4
    const int NW2 = DOUT * DHID / 4;  // 16384 float4
    int id = blockIdx.x * 256 + threadIdx.x;
    const float* src; unsigned short *dh, *dl; int off;
    if (id < NW1)            { src = W1; dh = W1hi; dl = W1lo; off = id; }
    else if (id < NW1 + NW2) { src = W2; dh = W2hi; dl = W2lo; off = id - NW1; }
    else return;
    float4 x = ((const float4*)src)[off];
    float xs[4] = {x.x, x.y, x.z, x.w};
    unsigned int hp[2], lp[2];
    #pragma unroll
    for (int p = 0; p < 2; ++p) {
        unsigned int u0 = __float_as_uint(xs[p*2]);
        unsigned int u1 = __float_as_uint(xs[p*2+1]);
        float r0 = xs[p*2]   - __uint_as_float(u0 & 0xffff0000u);
        float r1 = xs[p*2+1] - __uint_as_float(u1 & 0xffff0000u);
        hp[p] = (u0 >> 16) | (u1 & 0xffff0000u);
        lp[p] = (__float_as_uint(r0) >> 16) | (__float_as_uint(r1) & 0xffff0000u);
    }
    ((uint2*)dh)[off] = make_uint2(hp[0], hp[1]);
    ((uint2*)dl)[off] = make_uint2(lp[0], lp[1]);
}

// ------- GEMM1 (MFMA bf16x2): Y = [h1;h2] @ W1^T + b1, fused BN col-sums ---
__global__ __launch_bounds__(256) void gemm1_mfma(
    const float* __restrict__ h1, const float* __restrict__ h2,
    const unsigned short* __restrict__ W1hi, const unsigned short* __restrict__ W1lo,
    const float* __restrict__ b1,
    float* __restrict__ Y, float* __restrict__ psumc, float* __restrict__ psqc)
{
    const int t = threadIdx.x;
    const int wave = t >> 6, lane = t & 63;
    const int quad = lane >> 4, l15 = lane & 15;
    const int mb = blockIdx.x;
    const int m0 = mb * 128 + wave * 32;
    const int n0 = blockIdx.y * 64;
    const int v  = (mb >= 32);

    short8 ahi[2][6], alo[2][6];
    #pragma unroll
    for (int mt = 0; mt < 2; ++mt) {
        int row = m0 + mt * 16 + l15;
        const float* hsrc = (row < NB) ? (h1 + (size_t)row * DIN)
                                       : (h2 + (size_t)(row - NB) * DIN);
        #pragma unroll
        for (int kc = 0; kc < 6; ++kc) {
            const float4* p = (const float4*)(hsrc + kc * 32 + quad * 8);
            float4 x0 = p[0], x1 = p[1];
            float xs[8] = {x0.x,x0.y,x0.z,x0.w,x1.x,x1.y,x1.z,x1.w};
            split8(xs, ahi[mt][kc], alo[mt][kc]);
        }
    }

    #pragma unroll
    for (int nt = 0; nt < 4; ++nt) {
        const int col = n0 + nt * 16 + l15;
        const short8* bh = (const short8*)(W1hi + (size_t)col * DIN + quad * 8);
        const short8* bl = (const short8*)(W1lo + (size_t)col * DIN + quad * 8);
        short8 bhi[6], blo[6];
        #pragma unroll
        for (int kc = 0; kc < 6; ++kc) { bhi[kc] = bh[kc * 4]; blo[kc] = bl[kc * 4]; }
        floatx4 acc[2] = {{0.f,0.f,0.f,0.f},{0.f,0.f,0.f,0.f}};
        #pragma unroll
        for (int kc = 0; kc < 6; ++kc)
            #pragma unroll
            for (int mt = 0; mt < 2; ++mt) {
                acc[mt] = __builtin_amdgcn_mfma_f32_16x16x32_bf16(alo[mt][kc], bhi[kc], acc[mt], 0,0,0);
                acc[mt] = __builtin_amdgcn_mfma_f32_16x16x32_bf16(ahi[mt][kc], blo[kc], acc[mt], 0,0,0);
                acc[mt] = __builtin_amdgcn_mfma_f32_16x16x32_bf16(ahi[mt][kc], bhi[kc], acc[mt], 0,0,0);
            }
        const float bias = b1[col];
        float cs = 0.f, cq = 0.f;
        #pragma unroll
        for (int mt = 0; mt < 2; ++mt)
            #pragma unroll
            for (int reg = 0; reg < 4; ++reg) {
                float y = acc[mt][reg] + bias;
                int row = m0 + mt * 16 + quad * 4 + reg;
                Y[(size_t)row * DHID + col] = y;
                cs += y; cq += y * y;
            }
        cs += __shfl_xor(cs, 16); cs += __shfl_xor(cs, 32);
        cq += __shfl_xor(cq, 16); cq += __shfl_xor(cq, 32);
        if (quad == 0) {
            atomicAdd(psumc + v * DHID + col, cs);
            atomicAdd(psqc  + v * DHID + col, cq);
        }
    }
}

#define ZSCALE 1.6986436f   // sqrt(2*log2(e)); Zb = z*ZSCALE so dot = exp2 arg

// ---- GEMM2 (MFMA bf16x2): z = relu(bn(Y)) @ W2^T + b2, L2-norm ------------
// W2hi/lo K-chunks double-buffered in LDS; bn-finalize fused; 8 waves of
// (16 rows x 16 cols); Y prefetched 1 stage ahead. grid 512 x 512 thr.
__global__ __launch_bounds__(512) void gemm2_mfma(
    const float* __restrict__ Y,
    const unsigned short* __restrict__ W2hi, const unsigned short* __restrict__ W2lo,
    const float* __restrict__ psumc, const float* __restrict__ psqc,
    const float* __restrict__ gamma, const float* __restrict__ beta,
    const float* __restrict__ b2,
    unsigned short* __restrict__ Zb, float* __restrict__ outz)
{
    __shared__ __align__(16) unsigned short Whs[2][128][40];  // padded stride
    __shared__ __align__(16) unsigned short Wls[2][128][40];
    __shared__ float sc_sh[DHID], sh_sh[DHID];
    __shared__ float sq_lds[8][16];
    const int t = threadIdx.x;          // 0..511
    const int wave = t >> 6, lane = t & 63;
    const int quad = lane >> 4, l15 = lane & 15;
    const int mtbase = blockIdx.x * 16;
    const int v = (mtbase >= NB);
    const int col = wave * 16 + l15;    // this wave's output col

    for (int c = t; c < DHID; c += 512) {
        float mean = psumc[v * DHID + c] * (1.0f / NB);
        float var  = psqc [v * DHID + c] * (1.0f / NB) - mean * mean;
        float rstd = rsqrtf(var + 1e-5f);
        float scv = gamma[c] * rstd;
        sc_sh[c] = scv;
        sh_sh[c] = beta[c] - mean * scv;
    }

    const int wc = t >> 2, wp = (t & 3) * 8;   // coop-load: col chunk, offset
    const float* yrow = Y + (size_t)(mtbase + l15) * DHID;

    uint4 gh[2], gl[2];
    gh[0] = *(const uint4*)(W2hi + (size_t)wc * DHID + wp);
    gl[0] = *(const uint4*)(W2lo + (size_t)wc * DHID + wp);
    *(uint4*)&Whs[0][wc][wp] = gh[0];
    *(uint4*)&Wls[0][wc][wp] = gl[0];
    gh[1] = *(const uint4*)(W2hi + (size_t)wc * DHID + 32 + wp);
    gl[1] = *(const uint4*)(W2lo + (size_t)wc * DHID + 32 + wp);
    float4 yc0 = *(const float4*)(yrow + quad * 8);
    float4 yc1 = *(const float4*)(yrow + quad * 8 + 4);
    __syncthreads();

    floatx4 acc = {0.f, 0.f, 0.f, 0.f};
    for (int s = 0; s < 16; ++s) {
        const int cur = s & 1, nxt = cur ^ 1;
        float4 yn0, yn1;
        if (s + 1 < 16) {
            yn0 = *(const float4*)(yrow + (s + 1) * 32 + quad * 8);
            yn1 = *(const float4*)(yrow + (s + 1) * 32 + quad * 8 + 4);
        }
        if (s + 2 < 16) {
            gh[cur] = *(const uint4*)(W2hi + (size_t)wc * DHID + (s + 2) * 32 + wp);
            gl[cur] = *(const uint4*)(W2lo + (size_t)wc * DHID + (s + 2) * 32 + wp);
        }
        if (s + 1 < 16) {
            *(uint4*)&Whs[nxt][wc][wp] = gh[nxt];
            *(uint4*)&Wls[nxt][wc][wp] = gl[nxt];
        }
        const int k = s * 32 + quad * 8;
        const float4 s0 = *(const float4*)&sc_sh[k], s1 = *(const float4*)&sc_sh[k + 4];
        const float4 h0 = *(const float4*)&sh_sh[k], h1v = *(const float4*)&sh_sh[k + 4];
        float xs[8];
        xs[0] = fmaxf(yc0.x * s0.x + h0.x, 0.f);
        xs[1] = fmaxf(yc0.y * s0.y + h0.y, 0.f);
        xs[2] = fmaxf(yc0.z * s0.z + h0.z, 0.f);
        xs[3] = fmaxf(yc0.w * s0.w + h0.w, 0.f);
        xs[4] = fmaxf(yc1.x * s1.x + h1v.x, 0.f);
        xs[5] = fmaxf(yc1.y * s1.y + h1v.y, 0.f);
        xs[6] = fmaxf(yc1.z * s1.z + h1v.z, 0.f);
        xs[7] = fmaxf(yc1.w * s1.w + h1v.w, 0.f);
        short8 ahi, alo;
        split8(xs, ahi, alo);
        short8 bh = *(const short8*)&Whs[cur][col][quad * 8];
        short8 bl = *(const short8*)&Wls[cur][col][quad * 8];
        acc = __builtin_amdgcn_mfma_f32_16x16x32_bf16(alo, bh, acc, 0,0,0);
        acc = __builtin_amdgcn_mfma_f32_16x16x32_bf16(ahi, bl, acc, 0,0,0);
        acc = __builtin_amdgcn_mfma_f32_16x16x32_bf16(ahi, bh, acc, 0,0,0);
        yc0 = yn0; yc1 = yn1;
        __syncthreads();
    }

    const float bias = b2[col];
    float zv[4], sqp[4];
    #pragma unroll
    for (int reg = 0; reg < 4; ++reg) {
        zv[reg] = acc[reg] + bias;
        float q = zv[reg] * zv[reg];
        q += __shfl_xor(q, 1); q += __shfl_xor(q, 2);
        q += __shfl_xor(q, 4); q += __shfl_xor(q, 8);
        sqp[reg] = q;
        if (l15 == 0) sq_lds[wave][quad * 4 + reg] = q;
    }
    __syncthreads();
    #pragma unroll
    for (int reg = 0; reg < 4; ++reg) {
        float tot = 0.f;
        #pragma unroll
        for (int w = 0; w < 8; ++w) tot += sq_lds[w][quad * 4 + reg];
        float inv = 1.0f / fmaxf(sqrtf(tot), 1e-12f);
        const int row = mtbase + quad * 4 + reg;
        float z = zv[reg] * inv;
        outz[(size_t)row * DOUT + col] = z;
        Zb[(size_t)row * DOUT + col] = bf16_rne(z * ZSCALE);
    }
}

// ---- sim: psum_row = sum_cols exp2(Zb . Zb^T)  (diag included; subtracted
// in row_finalize). 4 waves x 32 rows; 512-col slice; B double-buffered in
// LDS (16 stages x 32 cols, padded stride 136). grid (64, NSPLIT) x 256 thr.
__global__ __launch_bounds__(256) void sim_mfma(
    const unsigned short* __restrict__ Zb, float* __restrict__ psum)
{
    __shared__ __align__(16) unsigned short Bsh[2][32][136];
    const int t = threadIdx.x;
    const int wave = t >> 6, lane = t & 63;
    const int quad = lane >> 4, l15 = lane & 15;
    const int mbase = blockIdx.x * 128 + wave * 32;
    const int cbase = blockIdx.y * 512;

    short8 a[2][4];
    #pragma unroll
    for (int at = 0; at < 2; ++at) {
        const short8* zra = (const short8*)(Zb + (size_t)(mbase + at * 16 + l15) * DOUT + quad * 8);
        #pragma unroll
        for (int kc = 0; kc < 4; ++kc) a[at][kc] = zra[kc * 4];
    }

    float rs[2][4] = {};
    const int c0i = t, c1i = t + 256;       // coop chunk ids (8 shorts each)
    const int r0i = c0i >> 4, o0i = (c0i & 15) * 8;
    const int r1i = c1i >> 4, o1i = (c1i & 15) * 8;

    uint4 g0[2], g1[2];
    {
        const uint4* gb0 = (const uint4*)(Zb + (size_t)cbase * DOUT);
        g0[0] = gb0[t]; g1[0] = gb0[t + 256];
        *(uint4*)&Bsh[0][r0i][o0i] = g0[0];
        *(uint4*)&Bsh[0][r1i][o1i] = g1[0];
        const uint4* gb1 = (const uint4*)(Zb + (size_t)(cbase + 32) * DOUT);
        g0[1] = gb1[t]; g1[1] = gb1[t + 256];
    }
    __syncthreads();

    for (int s = 0; s < 16; ++s) {
        const int cur = s & 1, nxt = cur ^ 1;
        if (s + 2 < 16) {
            const uint4* gb = (const uint4*)(Zb + (size_t)(cbase + (s + 2) * 32) * DOUT);
            g0[cur] = gb[t]; g1[cur] = gb[t + 256];
        }
        if (s + 1 < 16) {
            *(uint4*)&Bsh[nxt][r0i][o0i] = g0[nxt];
            *(uint4*)&Bsh[nxt][r1i][o1i] = g1[nxt];
        }
        #pragma unroll
        for (int ct = 0; ct < 2; ++ct) {
            short8 b[4];
            #pragma unroll
            for (int kc = 0; kc < 4; ++kc)
                b[kc] = *(const short8*)&Bsh[cur][ct * 16 + l15][kc * 32 + quad * 8];
            floatx4 acc[2] = {{0.f,0.f,0.f,0.f},{0.f,0.f,0.f,0.f}};
            #pragma unroll
            for (int kc = 0; kc < 4; ++kc)
                #pragma unroll
                for (int at = 0; at < 2; ++at)
                    acc[at] = __builtin_amdgcn_mfma_f32_16x16x32_bf16(a[at][kc], b[kc], acc[at], 0,0,0);
            #pragma unroll
            for (int at = 0; at < 2; ++at)
                #pragma unroll
                for (int r = 0; r < 4; ++r)
                    rs[at][r] += fast_exp2(acc[at][r]);
        }
        __syncthreads();
    }

    #pragma unroll
    for (int at = 0; at < 2; ++at) {
        const int gi0 = mbase + at * 16 + quad * 4;
        #pragma unroll
        for (int r = 0; r < 4; ++r) {
            float s = rs[at][r];
            s += __shfl_xor(s, 1); s += __shfl_xor(s, 2);
            s += __shfl_xor(s, 4); s += __shfl_xor(s, 8);
            if (l15 == 0) psum[(size_t)blockIdx.y * N2 + gi0 + r] = s;
        }
    }
}

// ---- per-row lse - pos, minus diag term; block-reduce -> atomic loss ------
__global__ __launch_bounds__(256) void row_finalize(
    const unsigned short* __restrict__ Zb, const float* __restrict__ psum,
    float* __restrict__ out)
{
    int i = blockIdx.x * 256 + threadIdx.x;
    float s = 0.f;
    #pragma unroll
    for (int cs = 0; cs < NSPLIT; ++cs) s += psum[(size_t)cs * N2 + i];
    int k = i & (NB - 1);
    const uint4* z1 = (const uint4*)(Zb + (size_t)k * DOUT);
    const uint4* z2 = (const uint4*)(Zb + (size_t)(k + NB) * DOUT);
    float d12 = 0.f, d11 = 0.f, d22 = 0.f;
    #pragma unroll
    for (int q = 0; q < 16; ++q) {
        uint4 a = z1[q], bqq = z2[q];
        const unsigned int aw[4] = {a.x, a.y, a.z, a.w};
        const unsigned int bw[4] = {bqq.x, bqq.y, bqq.z, bqq.w};
        #pragma unroll
        for (int c = 0; c < 4; ++c) {
            float alo = __uint_as_float(aw[c] << 16);
            float ahi = __uint_as_float(aw[c] & 0xffff0000u);
            float blo = __uint_as_float(bw[c] << 16);
            float bhi = __uint_as_float(bw[c] & 0xffff0000u);
            d12 += alo * blo + ahi * bhi;
            d11 += alo * alo + ahi * ahi;
            d22 += blo * blo + bhi * bhi;
        }
    }
    float dself = (i < NB) ? d11 : d22;
    // Zb is scaled: dot' = 2*log2(e)*dot => 2*dot = dot'*ln2; diag = exp2(dot')
    float rowval = logf(s - fast_exp2(dself)) - d12 * 0.69314718f;

    float r = rowval;
    r += __shfl_xor(r, 1);  r += __shfl_xor(r, 2);  r += __shfl_xor(r, 4);
    r += __shfl_xor(r, 8);  r += __shfl_xor(r, 16); r += __shfl_xor(r, 32);
    __shared__ float wsr[4];
    int lane = threadIdx.x & 63, w = threadIdx.x >> 6;
    if (lane == 0) wsr[w] = r;
    __syncthreads();
    if (threadIdx.x == 0)
        atomicAdd(out, (wsr[0] + wsr[1] + wsr[2] + wsr[3]) * (1.0f / N2));
}

extern "C" void kernel_launch(void* const* d_in, const int* in_sizes, int n_in,
                              void* d_out, int out_size, void* d_ws, size_t ws_size,
                              hipStream_t stream)
{
    const float* h1    = (const float*)d_in[0];
    const float* h2    = (const float*)d_in[1];
    const float* W1    = (const float*)d_in[2];
    const float* b1    = (const float*)d_in[3];
    const float* gamma = (const float*)d_in[4];
    const float* beta  = (const float*)d_in[5];
    const float* W2    = (const float*)d_in[6];
    const float* b2    = (const float*)d_in[7];
    float* out = (float*)d_out;

    float* ws      = (float*)d_ws;
    float* psumc   = ws;                            // 1024 f
    float* psqc    = psumc + 1024;                  // 1024 f
    unsigned short* W1hi = (unsigned short*)(psqc + 1024);  // 98304 us
    unsigned short* W1lo = W1hi + DHID * DIN;
    unsigned short* W2hi = W1lo + DHID * DIN;       // 65536 us
    unsigned short* W2lo = W2hi + DOUT * DHID;
    float* Y       = (float*)(W2lo + DOUT * DHID);  // 8192*512 = 4M f
    float* psum    = Y + (size_t)N2 * DHID;         // 16*8192 f
    unsigned short* Zb = (unsigned short*)(psum + (size_t)NSPLIT * N2); // 1M us
    // total ~18.6 MB

    hipMemsetAsync(psumc, 0, 2048 * sizeof(float), stream);  // psumc+psqc
    hipMemsetAsync(out, 0, sizeof(float), stream);           // loss accumulator

    convert_w   <<<dim3(160),        256, 0, stream>>>(W1, W2, W1hi, W1lo, W2hi, W2lo);
    gemm1_mfma  <<<dim3(64, 8),      256, 0, stream>>>(h1, h2, W1hi, W1lo, b1, Y, psumc, psqc);
    gemm2_mfma  <<<dim3(512),        512, 0, stream>>>(Y, W2hi, W2lo, psumc, psqc, gamma, beta, b2, Zb, out + 1);
    sim_mfma    <<<dim3(64, NSPLIT), 256, 0, stream>>>(Zb, psum);
    row_finalize<<<dim3(32),         256, 0, stream>>>(Zb, psum, out);
}

// Round 8
// 185.150 us; speedup vs baseline: 1.2531x; 1.2531x over previous
//
#include <hip/hip_runtime.h>

// SimCLR fused pipeline, round 8.
// sim: 64-col LDS stages (8 stages, 1 barrier each), dense block-shared B
//      loads, global->reg->LDS prefetch distance 2, 32 rows/wave (A=32 VGPR),
//      XCD-swizzled col-splits. Fixes r7's tiny-stage serialization and
//      r4's per-wave redundant sparse B streams.
// gemm1/gemm2: r6 versions (MFMA bf16x2, fused BN).

#define NB   4096
#define DIN  192
#define DHID 512
#define DOUT 128
#define N2   8192   // 2*NB
#define NSPLIT 16   // sim col-splits; 512 cols per block

typedef short short8 __attribute__((ext_vector_type(8)));   // 8 bf16 (4 VGPRs)
typedef float floatx4 __attribute__((ext_vector_type(4)));  // MFMA C/D frag

__device__ inline float fast_exp2(float x) {
#if __has_builtin(__builtin_amdgcn_exp2f)
    return __builtin_amdgcn_exp2f(x);
#else
    return exp2f(x);
#endif
}

// Truncation-based Dekker split: x ~= hi + lo with |err| < 2^-16 |x|.
__device__ inline void split8(const float* x, short8& hi, short8& lo) {
    #pragma unroll
    for (int j = 0; j < 8; ++j) {
        unsigned int u = __float_as_uint(x[j]);
        float hf = __uint_as_float(u & 0xffff0000u);
        float r = x[j] - hf;                       // exact
        hi[j] = (short)(u >> 16);
        lo[j] = (short)(__float_as_uint(r) >> 16);
    }
}

__device__ inline unsigned short bf16_rne(float x) {
    unsigned int u = __float_as_uint(x);
    return (unsigned short)((u + 0x7fffu + ((u >> 16) & 1u)) >> 16);
}

// ---------------- convert W1, W2 -> hi/lo bf16 ------------------------------
__global__ __launch_bounds__(256) void convert_w(
    const float* __restrict__ W1, const float* __restrict__ W2,
    unsigned short* __restrict__ W1hi, unsigned short* __restrict__ W1lo,
    unsigned short* __restrict__ W2hi, unsigned short* __restrict__ W2lo)
{
    const int NW1 = DHID * DIN / 4;   // 24576 float4
    const int NW2 = DOUT * DHID / 4;  // 16384 float4
    int id = blockIdx.x * 256 + threadIdx.x;
    const float* src; unsigned short *dh, *dl; int off;
    if (id < NW1)            { src = W1; dh = W1hi; dl = W1lo; off = id; }
    else if (id < NW1 + NW2) { src = W2; dh = W2hi; dl = W2lo; off = id - NW1; }
    else return;
    float4 x = ((const float4*)src)[off];
    float xs[4] = {x.x, x.y, x.z, x.w};
    unsigned int hp[2], lp[2];
    #pragma unroll
    for (int p = 0; p < 2; ++p) {
        unsigned int u0 = __float_as_uint(xs[p*2]);
        unsigned int u1 = __float_as_uint(xs[p*2+1]);
        float r0 = xs[p*2]   - __uint_as_float(u0 & 0xffff0000u);
        float r1 = xs[p*2+1] - __uint_as_float(u1 & 0xffff0000u);
        hp[p] = (u0 >> 16) | (u1 & 0xffff0000u);
        lp[p] = (__float_as_uint(r0) >> 16) | (__float_as_uint(r1) & 0xffff0000u);
    }
    ((uint2*)dh)[off] = make_uint2(hp[0], hp[1]);
    ((uint2*)dl)[off] = make_uint2(lp[0], lp[1]);
}

// ------- GEMM1 (MFMA bf16x2): Y = [h1;h2] @ W1^T + b1, fused BN col-sums ---
__global__ __launch_bounds__(256) void gemm1_mfma(
    const float* __restrict__ h1, const float* __restrict__ h2,
    const unsigned short* __restrict__ W1hi, const unsigned short* __restrict__ W1lo,
    const float* __restrict__ b1,
    float* __restrict__ Y, float* __restrict__ psumc, float* __restrict__ psqc)
{
    const int t = threadIdx.x;
    const int wave = t >> 6, lane = t & 63;
    const int quad = lane >> 4, l15 = lane & 15;
    const int mb = blockIdx.x;
    const int m0 = mb * 128 + wave * 32;
    const int n0 = blockIdx.y * 64;
    const int v  = (mb >= 32);

    short8 ahi[2][6], alo[2][6];
    #pragma unroll
    for (int mt = 0; mt < 2; ++mt) {
        int row = m0 + mt * 16 + l15;
        const float* hsrc = (row < NB) ? (h1 + (size_t)row * DIN)
                                       : (h2 + (size_t)(row - NB) * DIN);
        #pragma unroll
        for (int kc = 0; kc < 6; ++kc) {
            const float4* p = (const float4*)(hsrc + kc * 32 + quad * 8);
            float4 x0 = p[0], x1 = p[1];
            float xs[8] = {x0.x,x0.y,x0.z,x0.w,x1.x,x1.y,x1.z,x1.w};
            split8(xs, ahi[mt][kc], alo[mt][kc]);
        }
    }

    #pragma unroll
    for (int nt = 0; nt < 4; ++nt) {
        const int col = n0 + nt * 16 + l15;
        const short8* bh = (const short8*)(W1hi + (size_t)col * DIN + quad * 8);
        const short8* bl = (const short8*)(W1lo + (size_t)col * DIN + quad * 8);
        short8 bhi[6], blo[6];
        #pragma unroll
        for (int kc = 0; kc < 6; ++kc) { bhi[kc] = bh[kc * 4]; blo[kc] = bl[kc * 4]; }
        floatx4 acc[2] = {{0.f,0.f,0.f,0.f},{0.f,0.f,0.f,0.f}};
        #pragma unroll
        for (int kc = 0; kc < 6; ++kc)
            #pragma unroll
            for (int mt = 0; mt < 2; ++mt) {
                acc[mt] = __builtin_amdgcn_mfma_f32_16x16x32_bf16(alo[mt][kc], bhi[kc], acc[mt], 0,0,0);
                acc[mt] = __builtin_amdgcn_mfma_f32_16x16x32_bf16(ahi[mt][kc], blo[kc], acc[mt], 0,0,0);
                acc[mt] = __builtin_amdgcn_mfma_f32_16x16x32_bf16(ahi[mt][kc], bhi[kc], acc[mt], 0,0,0);
            }
        const float bias = b1[col];
        float cs = 0.f, cq = 0.f;
        #pragma unroll
        for (int mt = 0; mt < 2; ++mt)
            #pragma unroll
            for (int reg = 0; reg < 4; ++reg) {
                float y = acc[mt][reg] + bias;
                int row = m0 + mt * 16 + quad * 4 + reg;
                Y[(size_t)row * DHID + col] = y;
                cs += y; cq += y * y;
            }
        cs += __shfl_xor(cs, 16); cs += __shfl_xor(cs, 32);
        cq += __shfl_xor(cq, 16); cq += __shfl_xor(cq, 32);
        if (quad == 0) {
            atomicAdd(psumc + v * DHID + col, cs);
            atomicAdd(psqc  + v * DHID + col, cq);
        }
    }
}

#define ZSCALE 1.6986436f   // sqrt(2*log2(e)); Zb = z*ZSCALE so dot = exp2 arg

// ---- GEMM2 (MFMA bf16x2): z = relu(bn(Y)) @ W2^T + b2, L2-norm ------------
// bn-finalize fused (per-block, into LDS). N-split x2: wave = 16 rows x 64
// cols, K=512; wave-pair combines row-sq via LDS. grid 512 x 128 thr.
__global__ __launch_bounds__(128) void gemm2_mfma(
    const float* __restrict__ Y,
    const unsigned short* __restrict__ W2hi, const unsigned short* __restrict__ W2lo,
    const float* __restrict__ psumc, const float* __restrict__ psqc,
    const float* __restrict__ gamma, const float* __restrict__ beta,
    const float* __restrict__ b2,
    unsigned short* __restrict__ Zb, float* __restrict__ outz)
{
    __shared__ float sc_sh[DHID], sh_sh[DHID];
    __shared__ float sq_lds[2][16];
    const int t = threadIdx.x;
    const int wave = t >> 6, lane = t & 63;
    const int quad = lane >> 4, l15 = lane & 15;
    const int mtbase = blockIdx.x * 16;
    const int v = (mtbase >= NB);

    for (int c = t; c < DHID; c += 128) {
        float mean = psumc[v * DHID + c] * (1.0f / NB);
        float var  = psqc [v * DHID + c] * (1.0f / NB) - mean * mean;
        float rstd = rsqrtf(var + 1e-5f);
        float scv = gamma[c] * rstd;
        sc_sh[c] = scv;
        sh_sh[c] = beta[c] - mean * scv;
    }
    __syncthreads();

    const float* yrow = Y + (size_t)(mtbase + l15) * DHID;
    floatx4 acc[4] = {{0.f,0.f,0.f,0.f},{0.f,0.f,0.f,0.f},
                      {0.f,0.f,0.f,0.f},{0.f,0.f,0.f,0.f}};
    for (int kc = 0; kc < 16; ++kc) {
        const int k = kc * 32 + quad * 8;
        float4 y0 = *(const float4*)(yrow + k);
        float4 y1 = *(const float4*)(yrow + k + 4);
        float4 s0 = *(const float4*)&sc_sh[k], s1 = *(const float4*)&sc_sh[k + 4];
        float4 h0 = *(const float4*)&sh_sh[k], h1v = *(const float4*)&sh_sh[k + 4];
        float xs[8];
        xs[0] = fmaxf(y0.x * s0.x + h0.x, 0.f);
        xs[1] = fmaxf(y0.y * s0.y + h0.y, 0.f);
        xs[2] = fmaxf(y0.z * s0.z + h0.z, 0.f);
        xs[3] = fmaxf(y0.w * s0.w + h0.w, 0.f);
        xs[4] = fmaxf(y1.x * s1.x + h1v.x, 0.f);
        xs[5] = fmaxf(y1.y * s1.y + h1v.y, 0.f);
        xs[6] = fmaxf(y1.z * s1.z + h1v.z, 0.f);
        xs[7] = fmaxf(y1.w * s1.w + h1v.w, 0.f);
        short8 ahi, alo;
        split8(xs, ahi, alo);
        #pragma unroll
        for (int ntl = 0; ntl < 4; ++ntl) {
            const int col = (wave * 4 + ntl) * 16 + l15;
            const size_t colk = (size_t)col * DHID + k;
            short8 bh = *(const short8*)(W2hi + colk);
            short8 bl = *(const short8*)(W2lo + colk);
            acc[ntl] = __builtin_amdgcn_mfma_f32_16x16x32_bf16(alo, bh, acc[ntl], 0,0,0);
            acc[ntl] = __builtin_amdgcn_mfma_f32_16x16x32_bf16(ahi, bl, acc[ntl], 0,0,0);
            acc[ntl] = __builtin_amdgcn_mfma_f32_16x16x32_bf16(ahi, bh, acc[ntl], 0,0,0);
        }
    }
    float bias[4];
    #pragma unroll
    for (int ntl = 0; ntl < 4; ++ntl) bias[ntl] = b2[(wave * 4 + ntl) * 16 + l15];

    float zv[4][4];     // [reg][ntl]
    float sqp[4];
    #pragma unroll
    for (int reg = 0; reg < 4; ++reg) {
        float sq = 0.f;
        #pragma unroll
        for (int ntl = 0; ntl < 4; ++ntl) {
            zv[reg][ntl] = acc[ntl][reg] + bias[ntl];
            sq += zv[reg][ntl] * zv[reg][ntl];
        }
        sq += __shfl_xor(sq, 1); sq += __shfl_xor(sq, 2);
        sq += __shfl_xor(sq, 4); sq += __shfl_xor(sq, 8);
        sqp[reg] = sq;
        if (l15 == 0) sq_lds[wave][quad * 4 + reg] = sq;
    }
    __syncthreads();
    #pragma unroll
    for (int reg = 0; reg < 4; ++reg) {
        float tot = sqp[reg] + sq_lds[wave ^ 1][quad * 4 + reg];
        float inv = 1.0f / fmaxf(sqrtf(tot), 1e-12f);
        const int row = mtbase + quad * 4 + reg;
        const size_t ob = (size_t)row * DOUT;
        #pragma unroll
        for (int ntl = 0; ntl < 4; ++ntl) {
            const int col = (wave * 4 + ntl) * 16 + l15;
            float z = zv[reg][ntl] * inv;
            outz[ob + col] = z;
            Zb[ob + col] = bf16_rne(z * ZSCALE);
        }
    }
}

// ---- sim: psum_row = sum_cols exp2(Zb . Zb^T)  (diag included; subtracted
// in row_finalize). 4 waves x 32 rows; 512-col slice as 8 stages of 64 cols.
// B double-buffered in LDS (dense block-shared coop loads, prefetch dist 2,
// ONE barrier per stage). grid 1024 (XCD-swizzled) x 256 thr.
__global__ __launch_bounds__(256) void sim_mfma(
    const unsigned short* __restrict__ Zb, float* __restrict__ psum)
{
    __shared__ __align__(16) unsigned short Bsh[2][64][136];
    const int t = threadIdx.x;
    const int wave = t >> 6, lane = t & 63;
    const int quad = lane >> 4, l15 = lane & 15;
    // XCD swizzle: consecutive dispatch ids go to different XCDs (id%8).
    // Give XCD k col-splits {2k, 2k+1} so its L2 holds a small hot B set.
    const int n = blockIdx.x;
    const int xcd = n & 7, slot = n >> 3;
    const int cs = xcd * 2 + (slot >> 6);     // 0..15
    const int rb = slot & 63;                 // row-block 0..63
    const int mbase = rb * 128 + wave * 32;
    const int cbase = cs * 512;

    // A: 2 tiles x 4 kc, resident (32 VGPRs)
    short8 a[2][4];
    #pragma unroll
    for (int at = 0; at < 2; ++at) {
        const short8* zra = (const short8*)(Zb + (size_t)(mbase + at * 16 + l15) * DOUT + quad * 8);
        #pragma unroll
        for (int kc = 0; kc < 4; ++kc) a[at][kc] = zra[kc * 4];
    }

    float rs[2][4] = {};

    // coop load mapping: thread covers row lr (0..63), 4 uint4 chunks
    const int lr = t >> 2, lq = t & 3;
    const uint4* gsrc = (const uint4*)(Zb + (size_t)(cbase + lr) * DOUT);  // +stage*64 rows
    // one stage = 64 rows x 16 uint4; row stride in uint4 = DOUT*2/16 = 16
    uint4 g[2][4];   // [parity][chunk]

    // init: stage 0 -> LDS[0]; stage 1 -> g[1]
    #pragma unroll
    for (int j = 0; j < 4; ++j) g[0][j] = gsrc[lq + 4 * j];
    #pragma unroll
    for (int j = 0; j < 4; ++j) *(uint4*)&Bsh[0][lr][(lq + 4 * j) * 8] = g[0][j];
    #pragma unroll
    for (int j = 0; j < 4; ++j) g[1][j] = gsrc[64 * 16 + lq + 4 * j];
    __syncthreads();

    #pragma unroll
    for (int s = 0; s < 8; ++s) {
        const int cur = s & 1, nxt = cur ^ 1;
        // 1. issue loads for stage s+2 into g[cur] (its old data is in LDS)
        if (s + 2 < 8) {
            #pragma unroll
            for (int j = 0; j < 4; ++j)
                g[cur][j] = gsrc[(s + 2) * 64 * 16 + lq + 4 * j];
        }
        // 2. compute on LDS[cur]: 4 col-tiles of 16
        #pragma unroll
        for (int ct = 0; ct < 4; ++ct) {
            short8 b[4];
            #pragma unroll
            for (int kc = 0; kc < 4; ++kc)
                b[kc] = *(const short8*)&Bsh[cur][ct * 16 + l15][kc * 32 + quad * 8];
            floatx4 acc[2] = {{0.f,0.f,0.f,0.f},{0.f,0.f,0.f,0.f}};
            #pragma unroll
            for (int kc = 0; kc < 4; ++kc)
                #pragma unroll
                for (int at = 0; at < 2; ++at)
                    acc[at] = __builtin_amdgcn_mfma_f32_16x16x32_bf16(a[at][kc], b[kc], acc[at], 0,0,0);
            #pragma unroll
            for (int at = 0; at < 2; ++at)
                #pragma unroll
                for (int r = 0; r < 4; ++r)
                    rs[at][r] += fast_exp2(acc[at][r]);
        }
        // 3. write stage s+1 (in g[nxt], loaded one stage ago) to LDS[nxt]
        if (s + 1 < 8) {
            #pragma unroll
            for (int j = 0; j < 4; ++j)
                *(uint4*)&Bsh[nxt][lr][(lq + 4 * j) * 8] = g[nxt][j];
        }
        // 4. one barrier: separates stage-s reads from stage-s+1's overwrite
        __syncthreads();
    }

    #pragma unroll
    for (int at = 0; at < 2; ++at) {
        const int gi0 = mbase + at * 16 + quad * 4;
        #pragma unroll
        for (int r = 0; r < 4; ++r) {
            float s = rs[at][r];
            s += __shfl_xor(s, 1); s += __shfl_xor(s, 2);
            s += __shfl_xor(s, 4); s += __shfl_xor(s, 8);
            if (l15 == 0) psum[(size_t)cs * N2 + gi0 + r] = s;
        }
    }
}

// ---- per-row lse - pos, minus diag term; block-reduce -> atomic loss ------
__global__ __launch_bounds__(256) void row_finalize(
    const unsigned short* __restrict__ Zb, const float* __restrict__ psum,
    float* __restrict__ out)
{
    int i = blockIdx.x * 256 + threadIdx.x;
    float s = 0.f;
    #pragma unroll
    for (int cs = 0; cs < NSPLIT; ++cs) s += psum[(size_t)cs * N2 + i];
    int k = i & (NB - 1);
    const uint4* z1 = (const uint4*)(Zb + (size_t)k * DOUT);
    const uint4* z2 = (const uint4*)(Zb + (size_t)(k + NB) * DOUT);
    float d12 = 0.f, d11 = 0.f, d22 = 0.f;
    #pragma unroll
    for (int q = 0; q < 16; ++q) {
        uint4 a = z1[q], bqq = z2[q];
        const unsigned int aw[4] = {a.x, a.y, a.z, a.w};
        const unsigned int bw[4] = {bqq.x, bqq.y, bqq.z, bqq.w};
        #pragma unroll
        for (int c = 0; c < 4; ++c) {
            float alo = __uint_as_float(aw[c] << 16);
            float ahi = __uint_as_float(aw[c] & 0xffff0000u);
            float blo = __uint_as_float(bw[c] << 16);
            float bhi = __uint_as_float(bw[c] & 0xffff0000u);
            d12 += alo * blo + ahi * bhi;
            d11 += alo * alo + ahi * ahi;
            d22 += blo * blo + bhi * bhi;
        }
    }
    float dself = (i < NB) ? d11 : d22;
    // Zb is scaled: dot' = 2*log2(e)*dot => 2*dot = dot'*ln2; diag = exp2(dot')
    float rowval = logf(s - fast_exp2(dself)) - d12 * 0.69314718f;

    float r = rowval;
    r += __shfl_xor(r, 1);  r += __shfl_xor(r, 2);  r += __shfl_xor(r, 4);
    r += __shfl_xor(r, 8);  r += __shfl_xor(r, 16); r += __shfl_xor(r, 32);
    __shared__ float wsr[4];
    int lane = threadIdx.x & 63, w = threadIdx.x >> 6;
    if (lane == 0) wsr[w] = r;
    __syncthreads();
    if (threadIdx.x == 0)
        atomicAdd(out, (wsr[0] + wsr[1] + wsr[2] + wsr[3]) * (1.0f / N2));
}

extern "C" void kernel_launch(void* const* d_in, const int* in_sizes, int n_in,
                              void* d_out, int out_size, void* d_ws, size_t ws_size,
                              hipStream_t stream)
{
    const float* h1    = (const float*)d_in[0];
    const float* h2    = (const float*)d_in[1];
    const float* W1    = (const float*)d_in[2];
    const float* b1    = (const float*)d_in[3];
    const float* gamma = (const float*)d_in[4];
    const float* beta  = (const float*)d_in[5];
    const float* W2    = (const float*)d_in[6];
    const float* b2    = (const float*)d_in[7];
    float* out = (float*)d_out;

    float* ws      = (float*)d_ws;
    float* psumc   = ws;                            // 1024 f
    float* psqc    = psumc + 1024;                  // 1024 f
    unsigned short* W1hi = (unsigned short*)(psqc + 1024);  // 98304 us
    unsigned short* W1lo = W1hi + DHID * DIN;
    unsigned short* W2hi = W1lo + DHID * DIN;       // 65536 us
    unsigned short* W2lo = W2hi + DOUT * DHID;
    float* Y       = (float*)(W2lo + DOUT * DHID);  // 8192*512 = 4M f
    float* psum    = Y + (size_t)N2 * DHID;         // 16*8192 f
    unsigned short* Zb = (unsigned short*)(psum + (size_t)NSPLIT * N2); // 1M us
    // total ~18.6 MB

    hipMemsetAsync(psumc, 0, 2048 * sizeof(float), stream);  // psumc+psqc
    hipMemsetAsync(out, 0, sizeof(float), stream);           // loss accumulator

    convert_w   <<<dim3(160),   256, 0, stream>>>(W1, W2, W1hi, W1lo, W2hi, W2lo);
    gemm1_mfma  <<<dim3(64, 8), 256, 0, stream>>>(h1, h2, W1hi, W1lo, b1, Y, psumc, psqc);
    gemm2_mfma  <<<dim3(512),   128, 0, stream>>>(Y, W2hi, W2lo, psumc, psqc, gamma, beta, b2, Zb, out + 1);
    sim_mfma    <<<dim3(1024),  256, 0, stream>>>(Zb, psum);
    row_finalize<<<dim3(32),    256, 0, stream>>>(Zb, psum, out);
}

// Round 9
// 159.305 us; speedup vs baseline: 1.4564x; 1.1622x over previous
//
#include <hip/hip_runtime.h>

// SimCLR fused pipeline, round 9.
// Plain-bf16 GEMMs (no Dekker split: 3x fewer MFMAs, much lower VGPR).
// sim: r4-proven skeleton (64 rows/wave, dynamic loop, dist-1 prefetch with
//      register copy -> compiles lean ~VGPR 76) with VALU stripped:
//      maskless diag + prescaled Zb + raw v_exp.
// gemm1: fused BN col-sum atomics. gemm2: occupancy-first, bn-finalize fused.

#define NB   4096
#define DIN  192
#define DHID 512
#define DOUT 128
#define N2   8192   // 2*NB
#define NSPLIT 32   // sim col-splits; 256 cols per block
#define SIM_ITERS 16

typedef short short8 __attribute__((ext_vector_type(8)));   // 8 bf16 (4 VGPRs)
typedef float floatx4 __attribute__((ext_vector_type(4)));  // MFMA C/D frag

__device__ inline float fast_exp2(float x) {
#if __has_builtin(__builtin_amdgcn_exp2f)
    return __builtin_amdgcn_exp2f(x);
#else
    return exp2f(x);
#endif
}

__device__ inline unsigned short bf16_rne(float x) {
    unsigned int u = __float_as_uint(x);
    return (unsigned short)((u + 0x7fffu + ((u >> 16) & 1u)) >> 16);
}

// ---------------- convert W1, W2 -> bf16 ------------------------------------
__global__ __launch_bounds__(256) void convert_w(
    const float* __restrict__ W1, const float* __restrict__ W2,
    unsigned short* __restrict__ W1b, unsigned short* __restrict__ W2b)
{
    const int NW1 = DHID * DIN / 4;   // 24576 float4
    const int NW2 = DOUT * DHID / 4;  // 16384 float4
    int id = blockIdx.x * 256 + threadIdx.x;
    const float* src; unsigned short* dst; int off;
    if (id < NW1)            { src = W1; dst = W1b; off = id; }
    else if (id < NW1 + NW2) { src = W2; dst = W2b; off = id - NW1; }
    else return;
    float4 x = ((const float4*)src)[off];
    unsigned int p0 = bf16_rne(x.x) | ((unsigned int)bf16_rne(x.y) << 16);
    unsigned int p1 = bf16_rne(x.z) | ((unsigned int)bf16_rne(x.w) << 16);
    ((uint2*)dst)[off] = make_uint2(p0, p1);
}

// ------- GEMM1 (bf16 MFMA): Y = [h1;h2] @ W1^T + b1, fused BN col-sums -----
// grid (64 m-blocks of 128 rows, 8 n-splits of 64 cols), 256 thr (4 waves).
// Wave: 32 rows (2 mt) x 64 cols (4 nt), K=192 (6 kc).
__global__ __launch_bounds__(256) void gemm1_mfma(
    const float* __restrict__ h1, const float* __restrict__ h2,
    const unsigned short* __restrict__ W1b, const float* __restrict__ b1,
    float* __restrict__ Y, float* __restrict__ psumc, float* __restrict__ psqc)
{
    const int t = threadIdx.x;
    const int wave = t >> 6, lane = t & 63;
    const int quad = lane >> 4, l15 = lane & 15;
    const int mb = blockIdx.x;
    const int m0 = mb * 128 + wave * 32;
    const int n0 = blockIdx.y * 64;
    const int v  = (mb >= 32);

    short8 a[2][6];
    #pragma unroll
    for (int mt = 0; mt < 2; ++mt) {
        int row = m0 + mt * 16 + l15;
        const float* hsrc = (row < NB) ? (h1 + (size_t)row * DIN)
                                       : (h2 + (size_t)(row - NB) * DIN);
        #pragma unroll
        for (int kc = 0; kc < 6; ++kc) {
            const float4* p = (const float4*)(hsrc + kc * 32 + quad * 8);
            float4 x0 = p[0], x1 = p[1];
            float xs[8] = {x0.x,x0.y,x0.z,x0.w,x1.x,x1.y,x1.z,x1.w};
            #pragma unroll
            for (int j = 0; j < 8; ++j) a[mt][kc][j] = (short)bf16_rne(xs[j]);
        }
    }

    #pragma unroll
    for (int nt = 0; nt < 4; ++nt) {
        const int col = n0 + nt * 16 + l15;
        const short8* bptr = (const short8*)(W1b + (size_t)col * DIN + quad * 8);
        short8 b[6];
        #pragma unroll
        for (int kc = 0; kc < 6; ++kc) b[kc] = bptr[kc * 4];
        floatx4 acc[2] = {{0.f,0.f,0.f,0.f},{0.f,0.f,0.f,0.f}};
        #pragma unroll
        for (int kc = 0; kc < 6; ++kc)
            #pragma unroll
            for (int mt = 0; mt < 2; ++mt)
                acc[mt] = __builtin_amdgcn_mfma_f32_16x16x32_bf16(a[mt][kc], b[kc], acc[mt], 0,0,0);
        const float bias = b1[col];
        float cs = 0.f, cq = 0.f;
        #pragma unroll
        for (int mt = 0; mt < 2; ++mt)
            #pragma unroll
            for (int reg = 0; reg < 4; ++reg) {
                float y = acc[mt][reg] + bias;
                int row = m0 + mt * 16 + quad * 4 + reg;
                Y[(size_t)row * DHID + col] = y;
                cs += y; cq += y * y;
            }
        cs += __shfl_xor(cs, 16); cs += __shfl_xor(cs, 32);
        cq += __shfl_xor(cq, 16); cq += __shfl_xor(cq, 32);
        if (quad == 0) {
            atomicAdd(psumc + v * DHID + col, cs);
            atomicAdd(psqc  + v * DHID + col, cq);
        }
    }
}

#define ZSCALE 1.6986436f   // sqrt(2*log2(e)); Zb = z*ZSCALE so dot = exp2 arg

// ---- GEMM2 (bf16 MFMA): z = relu(bn(Y)) @ W2^T + b2, L2-norm --------------
// Block: 16 rows x 128 cols, 4 waves (wave w = cols w*32..+31, 2 nt).
// bn-finalize fused in prologue (LDS). 4-wave sq combine via LDS.
// grid 512 x 256 thr.
__global__ __launch_bounds__(256) void gemm2_mfma(
    const float* __restrict__ Y, const unsigned short* __restrict__ W2b,
    const float* __restrict__ psumc, const float* __restrict__ psqc,
    const float* __restrict__ gamma, const float* __restrict__ beta,
    const float* __restrict__ b2,
    unsigned short* __restrict__ Zb, float* __restrict__ outz)
{
    __shared__ float sc_sh[DHID], sh_sh[DHID];
    __shared__ float sq_lds[4][16];
    const int t = threadIdx.x;
    const int wave = t >> 6, lane = t & 63;
    const int quad = lane >> 4, l15 = lane & 15;
    const int mtbase = blockIdx.x * 16;
    const int v = (mtbase >= NB);

    for (int c = t; c < DHID; c += 256) {
        float mean = psumc[v * DHID + c] * (1.0f / NB);
        float var  = psqc [v * DHID + c] * (1.0f / NB) - mean * mean;
        float rstd = rsqrtf(var + 1e-5f);
        float scv = gamma[c] * rstd;
        sc_sh[c] = scv;
        sh_sh[c] = beta[c] - mean * scv;
    }
    __syncthreads();

    const float* yrow = Y + (size_t)(mtbase + l15) * DHID;
    floatx4 acc[2] = {{0.f,0.f,0.f,0.f},{0.f,0.f,0.f,0.f}};
    for (int kc = 0; kc < 16; ++kc) {
        const int k = kc * 32 + quad * 8;
        float4 y0 = *(const float4*)(yrow + k);
        float4 y1 = *(const float4*)(yrow + k + 4);
        float4 s0 = *(const float4*)&sc_sh[k], s1 = *(const float4*)&sc_sh[k + 4];
        float4 h0 = *(const float4*)&sh_sh[k], h1v = *(const float4*)&sh_sh[k + 4];
        float xs[8];
        xs[0] = fmaxf(y0.x * s0.x + h0.x, 0.f);
        xs[1] = fmaxf(y0.y * s0.y + h0.y, 0.f);
        xs[2] = fmaxf(y0.z * s0.z + h0.z, 0.f);
        xs[3] = fmaxf(y0.w * s0.w + h0.w, 0.f);
        xs[4] = fmaxf(y1.x * s1.x + h1v.x, 0.f);
        xs[5] = fmaxf(y1.y * s1.y + h1v.y, 0.f);
        xs[6] = fmaxf(y1.z * s1.z + h1v.z, 0.f);
        xs[7] = fmaxf(y1.w * s1.w + h1v.w, 0.f);
        short8 a;
        #pragma unroll
        for (int j = 0; j < 8; ++j) a[j] = (short)bf16_rne(xs[j]);
        #pragma unroll
        for (int nt = 0; nt < 2; ++nt) {
            const int col = wave * 32 + nt * 16 + l15;
            short8 b = *(const short8*)(W2b + (size_t)col * DHID + k);
            acc[nt] = __builtin_amdgcn_mfma_f32_16x16x32_bf16(a, b, acc[nt], 0,0,0);
        }
    }
    float bias[2];
    #pragma unroll
    for (int nt = 0; nt < 2; ++nt) bias[nt] = b2[wave * 32 + nt * 16 + l15];

    float zv[4][2];
    #pragma unroll
    for (int reg = 0; reg < 4; ++reg) {
        float sq = 0.f;
        #pragma unroll
        for (int nt = 0; nt < 2; ++nt) {
            zv[reg][nt] = acc[nt][reg] + bias[nt];
            sq += zv[reg][nt] * zv[reg][nt];
        }
        sq += __shfl_xor(sq, 1); sq += __shfl_xor(sq, 2);
        sq += __shfl_xor(sq, 4); sq += __shfl_xor(sq, 8);
        if (l15 == 0) sq_lds[wave][quad * 4 + reg] = sq;
    }
    __syncthreads();
    #pragma unroll
    for (int reg = 0; reg < 4; ++reg) {
        float tot = sq_lds[0][quad * 4 + reg] + sq_lds[1][quad * 4 + reg]
                  + sq_lds[2][quad * 4 + reg] + sq_lds[3][quad * 4 + reg];
        float inv = 1.0f / fmaxf(sqrtf(tot), 1e-12f);
        const int row = mtbase + quad * 4 + reg;
        const size_t ob = (size_t)row * DOUT;
        #pragma unroll
        for (int nt = 0; nt < 2; ++nt) {
            const int col = wave * 32 + nt * 16 + l15;
            float z = zv[reg][nt] * inv;
            outz[ob + col] = z;
            Zb[ob + col] = bf16_rne(z * ZSCALE);
        }
    }
}

// ---- sim: psum_row = sum_cols exp2(Zb . Zb^T)  (diag included; subtracted
// in row_finalize). r4-proven skeleton: wave owns 64 rows (4 A-tiles held in
// regs); dynamic loop, dist-1 double-buffered 16-col B-tile; 16 MFMA + 16 exp
// per iter. grid (32, NSPLIT) x 256 thr.
__global__ __launch_bounds__(256) void sim_mfma(
    const unsigned short* __restrict__ Zb, float* __restrict__ psum)
{
    const int t = threadIdx.x;
    const int wave = t >> 6, lane = t & 63;
    const int quad = lane >> 4, l15 = lane & 15;
    const int mbase = blockIdx.x * 256 + wave * 64;   // 64 rows per wave
    const int cs = blockIdx.y;                        // 0..NSPLIT-1
    const int cbase = cs * (N2 / NSPLIT);             // 256-col slice

    short8 a[4][4];
    #pragma unroll
    for (int at = 0; at < 4; ++at) {
        const short8* zra = (const short8*)(Zb + (size_t)(mbase + at * 16 + l15) * DOUT + quad * 8);
        #pragma unroll
        for (int kc = 0; kc < 4; ++kc) a[at][kc] = zra[kc * 4];
    }

    float rs[4][4];
    #pragma unroll
    for (int at = 0; at < 4; ++at)
        #pragma unroll
        for (int r = 0; r < 4; ++r) rs[at][r] = 0.f;

    short8 bcur[4], bnext[4];
    {
        const short8* zb = (const short8*)(Zb + (size_t)(cbase + l15) * DOUT + quad * 8);
        #pragma unroll
        for (int kc = 0; kc < 4; ++kc) bcur[kc] = zb[kc * 4];
    }

    for (int nt = 0; nt < SIM_ITERS; ++nt) {
        const int cn = cbase + ((nt + 1) & (SIM_ITERS - 1)) * 16;
        const short8* zbn = (const short8*)(Zb + (size_t)(cn + l15) * DOUT + quad * 8);
        #pragma unroll
        for (int kc = 0; kc < 4; ++kc) bnext[kc] = zbn[kc * 4];

        floatx4 acc[4] = {{0.f,0.f,0.f,0.f},{0.f,0.f,0.f,0.f},
                          {0.f,0.f,0.f,0.f},{0.f,0.f,0.f,0.f}};
        #pragma unroll
        for (int kc = 0; kc < 4; ++kc)
            #pragma unroll
            for (int at = 0; at < 4; ++at)
                acc[at] = __builtin_amdgcn_mfma_f32_16x16x32_bf16(a[at][kc], bcur[kc], acc[at], 0, 0, 0);

        #pragma unroll
        for (int at = 0; at < 4; ++at)
            #pragma unroll
            for (int r = 0; r < 4; ++r)
                rs[at][r] += fast_exp2(acc[at][r]);

        #pragma unroll
        for (int kc = 0; kc < 4; ++kc) bcur[kc] = bnext[kc];
    }

    #pragma unroll
    for (int at = 0; at < 4; ++at) {
        const int gi0 = mbase + at * 16 + quad * 4;
        #pragma unroll
        for (int r = 0; r < 4; ++r) {
            float s = rs[at][r];
            s += __shfl_xor(s, 1);
            s += __shfl_xor(s, 2);
            s += __shfl_xor(s, 4);
            s += __shfl_xor(s, 8);
            if (l15 == 0) psum[(size_t)cs * N2 + gi0 + r] = s;
        }
    }
}

// ---- per-row lse - pos, minus diag term; block-reduce -> atomic loss ------
__global__ __launch_bounds__(256) void row_finalize(
    const unsigned short* __restrict__ Zb, const float* __restrict__ psum,
    float* __restrict__ out)
{
    int i = blockIdx.x * 256 + threadIdx.x;
    float s = 0.f;
    #pragma unroll
    for (int cs = 0; cs < NSPLIT; ++cs) s += psum[(size_t)cs * N2 + i];
    int k = i & (NB - 1);
    const uint4* z1 = (const uint4*)(Zb + (size_t)k * DOUT);
    const uint4* z2 = (const uint4*)(Zb + (size_t)(k + NB) * DOUT);
    float d12 = 0.f, d11 = 0.f, d22 = 0.f;
    #pragma unroll
    for (int q = 0; q < 16; ++q) {
        uint4 a = z1[q], bqq = z2[q];
        const unsigned int aw[4] = {a.x, a.y, a.z, a.w};
        const unsigned int bw[4] = {bqq.x, bqq.y, bqq.z, bqq.w};
        #pragma unroll
        for (int c = 0; c < 4; ++c) {
            float alo = __uint_as_float(aw[c] << 16);
            float ahi = __uint_as_float(aw[c] & 0xffff0000u);
            float blo = __uint_as_float(bw[c] << 16);
            float bhi = __uint_as_float(bw[c] & 0xffff0000u);
            d12 += alo * blo + ahi * bhi;
            d11 += alo * alo + ahi * ahi;
            d22 += blo * blo + bhi * bhi;
        }
    }
    float dself = (i < NB) ? d11 : d22;
    // Zb is scaled: dot' = 2*log2(e)*dot => 2*dot = dot'*ln2; diag = exp2(dot')
    float rowval = logf(s - fast_exp2(dself)) - d12 * 0.69314718f;

    float r = rowval;
    r += __shfl_xor(r, 1);  r += __shfl_xor(r, 2);  r += __shfl_xor(r, 4);
    r += __shfl_xor(r, 8);  r += __shfl_xor(r, 16); r += __shfl_xor(r, 32);
    __shared__ float wsr[4];
    int lane = threadIdx.x & 63, w = threadIdx.x >> 6;
    if (lane == 0) wsr[w] = r;
    __syncthreads();
    if (threadIdx.x == 0)
        atomicAdd(out, (wsr[0] + wsr[1] + wsr[2] + wsr[3]) * (1.0f / N2));
}

extern "C" void kernel_launch(void* const* d_in, const int* in_sizes, int n_in,
                              void* d_out, int out_size, void* d_ws, size_t ws_size,
                              hipStream_t stream)
{
    const float* h1    = (const float*)d_in[0];
    const float* h2    = (const float*)d_in[1];
    const float* W1    = (const float*)d_in[2];
    const float* b1    = (const float*)d_in[3];
    const float* gamma = (const float*)d_in[4];
    const float* beta  = (const float*)d_in[5];
    const float* W2    = (const float*)d_in[6];
    const float* b2    = (const float*)d_in[7];
    float* out = (float*)d_out;

    float* ws      = (float*)d_ws;
    float* psumc   = ws;                            // 1024 f
    float* psqc    = psumc + 1024;                  // 1024 f
    unsigned short* W1b = (unsigned short*)(psqc + 1024);   // 98304 us
    unsigned short* W2b = W1b + DHID * DIN;         // 65536 us
    float* Y       = (float*)(W2b + DOUT * DHID);   // 8192*512 = 4M f
    float* psum    = Y + (size_t)N2 * DHID;         // 32*8192 f
    unsigned short* Zb = (unsigned short*)(psum + (size_t)NSPLIT * N2); // 1M us
    // total ~20.3 MB

    hipMemsetAsync(psumc, 0, 2048 * sizeof(float), stream);  // psumc+psqc
    hipMemsetAsync(out, 0, sizeof(float), stream);           // loss accumulator

    convert_w   <<<dim3(160),        256, 0, stream>>>(W1, W2, W1b, W2b);
    gemm1_mfma  <<<dim3(64, 8),      256, 0, stream>>>(h1, h2, W1b, b1, Y, psumc, psqc);
    gemm2_mfma  <<<dim3(512),        256, 0, stream>>>(Y, W2b, psumc, psqc, gamma, beta, b2, Zb, out + 1);
    sim_mfma    <<<dim3(32, NSPLIT), 256, 0, stream>>>(Zb, psum);
    row_finalize<<<dim3(32),         256, 0, stream>>>(Zb, psum, out);
}